// Round 17
// baseline (463.171 us; speedup 1.0000x reference)
//
#include <hip/hip_runtime.h>
#include <stdint.h>

// ---------------------------------------------------------------------------
// Problem constants
// ---------------------------------------------------------------------------
#define V_VOCAB 50257
#define V_PAD   51200          // 400 * 128 = 800 * 64
#define NROWS   8192           // 4 * 2048
#define DIM     512
#define KTOP    10
#define ACH     16             // amb rows per W-scan pass

typedef __attribute__((ext_vector_type(8))) short  short8;
typedef __attribute__((ext_vector_type(4))) float  f32x4;
typedef __attribute__((ext_vector_type(4))) int    i32x4;
typedef __attribute__((ext_vector_type(2))) unsigned int u32x2;

struct Ctrl { int mc; int namb; int hits; int pad_; };

// ws layout (bytes). Total ~31.6 MB.
#define OFF_WT8    0ULL
#define SZ_WT8     26214400ULL            // 51200*512 i8 (row = vocab col)
#define OFF_XQ8    (OFF_WT8 + SZ_WT8)
#define SZ_XQ8     4194304ULL             // 8192*512 i8
#define OFF_BPAD   (OFF_XQ8 + SZ_XQ8)
#define SZ_COL     (51200ULL*4)
#define OFF_SW8    (OFF_BPAD + SZ_COL)
#define OFF_W1     (OFF_SW8 + SZ_COL)
#define OFF_IVW    (OFF_W1 + SZ_COL)
#define OFF_ROWIDX (OFF_IVW + SZ_COL)
#define OFF_RMETA  (OFF_ROWIDX + 32768ULL) // f32x4 per row: {sx, that, etg', E}
#define OFF_COUNTS (OFF_RMETA + 131072ULL)
#define OFF_AMB    (OFF_COUNTS + 32768ULL)
#define OFF_CTRL   (OFF_AMB + 32768ULL)
#define OFF_RK     (OFF_CTRL + 16ULL)
#define OFF_SST    (OFF_RK + 32768ULL)

#define GLOAD16(gp, lp) __builtin_amdgcn_global_load_lds( \
    (const __attribute__((address_space(1))) unsigned int*)(gp), \
    (__attribute__((address_space(3))) unsigned int*)(lp), 16, 0, 0)

// ---------------------------------------------------------------------------
// 1. rowidx compaction (tiny)
// ---------------------------------------------------------------------------
__global__ void k_prep2(const int* __restrict__ mask, int* __restrict__ rowidx,
                        Ctrl* __restrict__ ctrl) {
  int i = blockIdx.x * 256 + threadIdx.x;
  if (i < NROWS && mask[i] != 0) {
    int p = atomicAdd(&ctrl->mc, 1);
    rowidx[p] = i;
  }
}

// ---------------------------------------------------------------------------
// 2a. per-col stats, 4-way k-split (R16 lesson: 200 blocks was 0.78/CU,
//     latency-starved on the cold W pass). Grid 800: 64 cols/block, thread
//     (c, kq) covers col c's k-quarter; LDS reduce. Also writes bpad.
// ---------------------------------------------------------------------------
__global__ void k_wstat2(const float* __restrict__ W, const float* __restrict__ b,
                         float* __restrict__ sw8, float* __restrict__ w1,
                         float* __restrict__ invw, float* __restrict__ bpad) {
  __shared__ float redm[4][64];
  __shared__ float reds[4][64];
  const int tid = threadIdx.x;
  const int c   = tid & 63;
  const int kq  = tid >> 6;          // 0..3
  const int j   = blockIdx.x * 64 + c;
  float am = 0.f, s1 = 0.f;
  if (j < V_VOCAB) {
    const float* p = W + (size_t)(kq * 128) * V_VOCAB + j;
#pragma unroll 4
    for (int k = 0; k < 128; ++k) {
      float v = fabsf(p[(size_t)k * V_VOCAB]);
      am = fmaxf(am, v);
      s1 += v;
    }
  }
  redm[kq][c] = am; reds[kq][c] = s1;
  __syncthreads();
  if (kq == 0) {
    am = fmaxf(fmaxf(redm[0][c], redm[1][c]), fmaxf(redm[2][c], redm[3][c]));
    s1 = reds[0][c] + reds[1][c] + reds[2][c] + reds[3][c];
    if (j < V_VOCAB) {
      sw8[j]  = (am > 0.f) ? am / 126.f : 1.f;
      invw[j] = (am > 0.f) ? 126.f / am : 0.f;
      w1[j]   = s1;
      bpad[j] = b[j];
    } else {
      sw8[j] = 1.f; invw[j] = 0.f; w1[j] = 0.f; bpad[j] = -1e30f;
    }
  }
}

// ---------------------------------------------------------------------------
// 2b. transpose+quantize: W f32[512][V] -> Wt8 i8[V_PAD][512]
// ---------------------------------------------------------------------------
__global__ void k_twt8(const float* __restrict__ W, const float* __restrict__ invw,
                       signed char* __restrict__ Wt8) {
  __shared__ float lt[64][65];
  const int vbase = blockIdx.x * 64;
  const int kbase = blockIdx.y * 64;
  const int tid = threadIdx.x;
  const int krow = tid >> 6;
  const int col  = tid & 63;
  const int v    = vbase + col;
#pragma unroll
  for (int rr = 0; rr < 16; ++rr) {
    int kl = krow + rr * 4;
    float val = (v < V_VOCAB) ? W[(size_t)(kbase + kl) * V_VOCAB + v] : 0.0f;
    lt[kl][col] = val;
  }
  __syncthreads();
  const int vr = tid >> 3;        // 0..31
  const int kc = tid & 7;
#pragma unroll
  for (int p = 0; p < 2; ++p) {
    const int vl = p * 32 + vr;
    const float inv = invw[vbase + vl];
    unsigned int lo = 0, hi = 0;
#pragma unroll
    for (int j = 0; j < 4; ++j) {
      int q = (int)rintf(lt[kc * 8 + j][vl] * inv);
      lo |= ((unsigned int)(q & 255)) << (8 * j);
    }
#pragma unroll
    for (int j = 0; j < 4; ++j) {
      int q = (int)rintf(lt[kc * 8 + 4 + j][vl] * inv);
      hi |= ((unsigned int)(q & 255)) << (8 * j);
    }
    u32x2 t; t.x = lo; t.y = hi;
    *(u32x2*)(Wt8 + (size_t)(vbase + vl) * DIM + kbase + kc * 8) = t;
  }
}

// ---------------------------------------------------------------------------
// 3. FUSED quantize + target score + row meta (was k_xq + k_that8).
//    Quantized row stays in registers for the target dot; d is an
//    order-free integer sum -> rmeta bitwise-identical to the 2-kernel
//    version. Saves one pass over Xq8 and one launch.
// ---------------------------------------------------------------------------
__global__ void k_xqt(const float* __restrict__ x, const int* __restrict__ rowidx,
                      const int* __restrict__ target,
                      const signed char* __restrict__ Wt8,
                      const float* __restrict__ bpad, const float* __restrict__ sw8,
                      const float* __restrict__ w1,
                      const Ctrl* __restrict__ ctrl,
                      signed char* __restrict__ Xq8, f32x4* __restrict__ rmeta) {
  const int wid = threadIdx.x >> 6, lane = threadIdx.x & 63;
  const int i = blockIdx.x * 4 + wid;
  const int mc = ctrl->mc;
  if (i >= mc) {
    u32x2 z; z.x = 0; z.y = 0;
    *(u32x2*)(Xq8 + (size_t)i * DIM + lane * 8) = z;
    if (lane == 0) { f32x4 rm; rm.x = 1.f; rm.y = 1e30f; rm.z = 0.f; rm.w = 0.f; rmeta[i] = rm; }
    return;
  }
  const int n  = rowidx[i];
  const int tg = target[n];
  const float* src = x + (size_t)n * DIM + lane * 8;
  float v[8];
  float am = 0.f, s1 = 0.f;
#pragma unroll
  for (int j = 0; j < 8; ++j) {
    v[j] = src[j];
    float a = fabsf(v[j]);
    am = fmaxf(am, a);
    s1 += a;
  }
#pragma unroll
  for (int d = 1; d < 64; d <<= 1) {
    am = fmaxf(am, __shfl_xor(am, d, 64));
    s1 += __shfl_xor(s1, d, 64);
  }
  const float sx  = (am > 0.f) ? am / 126.f : 1.f;
  const float inv = (am > 0.f) ? 126.f / am : 0.f;
  unsigned int lo = 0, hi = 0;
#pragma unroll
  for (int j = 0; j < 4; ++j) {
    int q = (int)rintf(v[j] * inv);
    lo |= ((unsigned int)(q & 255)) << (8 * j);
  }
#pragma unroll
  for (int j = 0; j < 4; ++j) {
    int q = (int)rintf(v[4 + j] * inv);
    hi |= ((unsigned int)(q & 255)) << (8 * j);
  }
  u32x2 t; t.x = lo; t.y = hi;
  *(u32x2*)(Xq8 + (size_t)i * DIM + lane * 8) = t;

  // target dot from the register copy (identical bytes to what was stored)
  u32x2 wq = *(const u32x2*)(Wt8 + (size_t)tg * DIM + lane * 8);
  int d = 0;
#pragma unroll
  for (int j = 0; j < 4; ++j)
    d += (int)((signed char)(lo >> (8 * j))) * (int)((signed char)(wq.x >> (8 * j)));
#pragma unroll
  for (int j = 0; j < 4; ++j)
    d += (int)((signed char)(hi >> (8 * j))) * (int)((signed char)(wq.y >> (8 * j)));
#pragma unroll
  for (int dd = 1; dd < 64; dd <<= 1) d += __shfl_xor(d, dd, 64);
  if (lane == 0) {
    const float sw = sw8[tg];
    f32x4 rm;
    rm.x = sx;
    rm.y = fmaf((float)d, sx * sw, bpad[tg]);                       // that
    rm.z = 0.5005f * (sx * w1[tg] + sw * s1) + 128.5f * (sx * sw)   // etg
           + 1e-3f;                                                 // + fp slop
    rm.w = fmaf(128.5f, sx, 0.5005f * s1);                          // E
    rmeta[i] = rm;
  }
}

// ---------------------------------------------------------------------------
// 5. fused i8 GEMM-count: R16's proven best (128x128 tile, BK=128 i8,
//    SINGLE 32KB LDS buffer, launch_bounds(256,3) -> 3-resident spill-free).
//    Changes vs R16: no setprio (m190: slightly negative on lockstep),
//    skip trailing barrier when no restage follows.
// ---------------------------------------------------------------------------
__launch_bounds__(256, 3)
__global__ void k_count8(const signed char* __restrict__ Xq8,
                         const signed char* __restrict__ Wt8,
                         const float* __restrict__ bpad, const float* __restrict__ sw8,
                         const float* __restrict__ w1, const f32x4* __restrict__ rmeta,
                         const Ctrl* __restrict__ ctrl, unsigned int* __restrict__ counts) {
  const int mc = ctrl->mc;
  // 12800 blocks = 8 XCDs x (4 m-tiles x 400 n-tiles), n-sweep per XCD
  const int lin = blockIdx.x;
  const int xcd = lin & 7;
  const int idx = lin >> 3;              // 0..1599
  const int mt  = xcd * 4 + (idx & 3);   // 0..31
  const int nt  = idx >> 2;              // 0..399
  const int nbase = nt * 128;

  __shared__ char lds[32768];            // single buffer: A 16KB + B 16KB

  const int tid  = threadIdx.x;
  const int lane = tid & 63;
  const int w    = tid >> 6;
  const int wr   = w >> 1;               // 0..1 : 64-row block
  const int wc   = w & 1;                // 0..1 : 64-col block

  const char* Bg = (const char*)Wt8 + (size_t)nbase * 512;
  const int r8   = tid >> 3;                                 // 0..31
  const int sws  = ((tid & 7) ^ (r8 & 7)) * 16;              // pre-swizzled src slot
  const int dst0 = tid * 16;

  const int fr = lane & 15;
  const int fq = lane >> 4;
  const int p0 = ((fq) ^ (fr & 7)) * 16;        // phys byte slot, k 0..63
  const int p1 = ((4 + fq) ^ (fr & 7)) * 16;    // k 64..127

#define STAGE(Ag, kt) do {                                                     \
    const size_t _kb = (size_t)(kt) * 128;                                     \
    _Pragma("unroll") for (int _c = 0; _c < 4; ++_c)                           \
      GLOAD16((Ag) + (size_t)(_c * 32 + r8) * 512 + _kb + sws,                 \
              lds + _c * 4096 + dst0);                                         \
    _Pragma("unroll") for (int _c = 0; _c < 4; ++_c)                           \
      GLOAD16(Bg + (size_t)(_c * 32 + r8) * 512 + _kb + sws,                   \
              lds + 16384 + _c * 4096 + dst0);                                 \
  } while (0)

#define KTILE() do {                                                           \
    _Pragma("unroll") for (int _ks = 0; _ks < 2; ++_ks) {                      \
      const int _p = _ks ? p1 : p0;                                            \
      i32x4 a4[4], b4[4];                                                      \
      _Pragma("unroll") for (int _i = 0; _i < 4; ++_i)                         \
        a4[_i] = *(const i32x4*)(lds + (wr * 64 + _i * 16 + fr) * 128 + _p);   \
      _Pragma("unroll") for (int _i = 0; _i < 4; ++_i)                         \
        b4[_i] = *(const i32x4*)(lds + 16384 +                                 \
                                 (wc * 64 + _i * 16 + fr) * 128 + _p);         \
      _Pragma("unroll") for (int _m = 0; _m < 4; ++_m)                         \
      _Pragma("unroll") for (int _n = 0; _n < 4; ++_n)                         \
        acc[_m][_n] = __builtin_amdgcn_mfma_i32_16x16x64_i8(                   \
            a4[_m], b4[_n], acc[_m][_n], 0, 0, 0);                             \
    }                                                                          \
  } while (0)

  i32x4 acc[4][4];

  // col meta (coalesced, loop-invariant)
  float bv[4], swc[4], w1c[4];
#pragma unroll
  for (int ni = 0; ni < 4; ++ni) {
    const int c = nbase + wc * 64 + ni * 16 + fr;
    bv[ni] = bpad[c]; swc[ni] = sw8[c]; w1c[ni] = w1[c];
  }

  for (int mb = mt * 128; mb < mc; mb += 4096) {
    const char* Ag = (const char*)Xq8 + (size_t)mb * 512;
#pragma unroll
    for (int a = 0; a < 4; ++a)
#pragma unroll
      for (int c = 0; c < 4; ++c) acc[a][c] = (i32x4)0;

#pragma unroll
    for (int kt = 0; kt < 4; ++kt) {
      STAGE(Ag, kt);
      __syncthreads();          // stage visible (compiler drains vmcnt)
      KTILE();
      if (kt < 3 || mb + 4096 < mc)
        __syncthreads();        // reads done before next stage overwrites
    }

    // epilogue: exact i32 -> f32 score, 2-fmaf margin, count, reduce, atomic
#pragma unroll
    for (int mi = 0; mi < 4; ++mi) {
#pragma unroll
      for (int r = 0; r < 4; ++r) {
        const int m = mb + wr * 64 + mi * 16 + fq * 4 + r;
        const f32x4 rm = rmeta[m];            // {sx, that, etg', E}
        const float arr = 0.5005f * rm.x;
        unsigned int p = 0;
#pragma unroll
        for (int ni = 0; ni < 4; ++ni) {
          const float s  = fmaf((float)acc[mi][ni][r], rm.x * swc[ni], bv[ni]);
          const float mm = fmaf(arr, w1c[ni], fmaf(rm.w, swc[ni], rm.z));
          p += (s > rm.y - mm) ? 1u : 0u;
          p += (s > rm.y + mm) ? (1u << 16) : 0u;
        }
        int pi = (int)p;
#pragma unroll
        for (int d = 1; d < 16; d <<= 1) pi += __shfl_xor(pi, d, 64);
        if ((lane & 15) == 0) atomicAdd(&counts[m], (unsigned int)pi);
      }
    }
  }
#undef STAGE
#undef KTILE
}

// ---------------------------------------------------------------------------
// 6. decide: certain hit / certain miss / ambiguous
// ---------------------------------------------------------------------------
__global__ void k_decide(const unsigned int* __restrict__ counts,
                         Ctrl* __restrict__ ctrl, int* __restrict__ amb) {
  const int i = blockIdx.x * 256 + threadIdx.x;
  if (i >= ctrl->mc) return;
  const unsigned int c = counts[i];
  const unsigned int lo = c & 0xFFFFu, hi = c >> 16;
  if (lo <= KTOP - 1) { atomicAdd(&ctrl->hits, 1); }
  else if (hi >= KTOP) { /* certain miss */ }
  else { int p = atomicAdd(&ctrl->namb, 1); amb[p] = i; }
}

// ---------------------------------------------------------------------------
// 7a. fixup targets (exact f32, sequential fmaf chain — must match k_fixscan)
// ---------------------------------------------------------------------------
__global__ void k_fixt(const float* __restrict__ x, const float* __restrict__ W,
                       const float* __restrict__ b, const int* __restrict__ rowidx,
                       const int* __restrict__ target, const int* __restrict__ amb,
                       const Ctrl* __restrict__ ctrl, float* __restrict__ sst) {
  const int a = blockIdx.x * 64 + threadIdx.x;
  if (a >= ctrl->namb) return;
  const int n = rowidx[amb[a]];
  const int tg = target[n];
  float st = 0.f;
  for (int k = 0; k < DIM; ++k)
    st = fmaf(x[(size_t)n * DIM + k], W[(size_t)k * V_VOCAB + tg], st);
  sst[a] = st + b[tg];
}

// ---------------------------------------------------------------------------
// 7b. fixup scan: one coalesced streaming pass over W for <=ACH rows at a time
// ---------------------------------------------------------------------------
__global__ void k_fixscan(const float* __restrict__ x, const float* __restrict__ W,
                          const float* __restrict__ b, const int* __restrict__ rowidx,
                          const int* __restrict__ target, const int* __restrict__ amb,
                          const float* __restrict__ sst, const Ctrl* __restrict__ ctrl,
                          int* __restrict__ rk) {
  __shared__ float sx[ACH][DIM];
  const int j = blockIdx.x * 256 + threadIdx.x;
  const int namb = ctrl->namb;
  const float bj = (j < V_VOCAB) ? b[j] : 0.f;
  for (int base = 0; base < namb; base += ACH) {
    __syncthreads();
    for (int t = threadIdx.x; t < ACH * DIM / 4; t += 256) {
      const int a  = t / (DIM / 4);
      const int kk = (t % (DIM / 4)) * 4;
      f32x4 v = (f32x4)0.f;
      if (base + a < namb) {
        const int n = rowidx[amb[base + a]];
        v = *(const f32x4*)(x + (size_t)n * DIM + kk);
      }
      *(f32x4*)(&sx[a][kk]) = v;
    }
    __syncthreads();
    if (j >= V_VOCAB) continue;
    float s[ACH];
#pragma unroll
    for (int a = 0; a < ACH; ++a) s[a] = 0.f;
    for (int k = 0; k < DIM; ++k) {
      const float wv = W[(size_t)k * V_VOCAB + j];
#pragma unroll
      for (int a = 0; a < ACH; ++a) s[a] = fmaf(sx[a][k], wv, s[a]);
    }
#pragma unroll
    for (int a = 0; a < ACH; ++a) {
      if (base + a < namb) {
        const int tg = target[rowidx[amb[base + a]]];
        const float sc = s[a] + bj;
        const float st = sst[base + a];
        if (sc > st || (sc == st && j < tg)) atomicAdd(&rk[base + a], 1);
      }
    }
  }
}

// ---------------------------------------------------------------------------
// 7c. fixup decide
// ---------------------------------------------------------------------------
__global__ void k_fixdec(const int* __restrict__ rk, Ctrl* __restrict__ ctrl) {
  const int a = blockIdx.x * 256 + threadIdx.x;
  if (a < ctrl->namb && rk[a] <= KTOP - 1) atomicAdd(&ctrl->hits, 1);
}

// ---------------------------------------------------------------------------
// 8. finalize
// ---------------------------------------------------------------------------
__global__ void k_final(const Ctrl* __restrict__ ctrl, float* __restrict__ out) {
  out[0] = (float)ctrl->hits / (float)ctrl->mc;
}

// ---------------------------------------------------------------------------
extern "C" void kernel_launch(void* const* d_in, const int* in_sizes, int n_in,
                              void* d_out, int out_size, void* d_ws, size_t ws_size,
                              hipStream_t stream) {
  const float* x      = (const float*)d_in[0];   // [8192, 512]
  const int*   target = (const int*)d_in[1];     // [8192]
  const int*   mask   = (const int*)d_in[2];     // [8192]
  const float* W      = (const float*)d_in[3];   // [512, 50257]
  const float* b      = (const float*)d_in[4];   // [50257]
  float* out = (float*)d_out;

  char* ws = (char*)d_ws;
  signed char*    Wt8    = (signed char*)(ws + OFF_WT8);
  signed char*    Xq8    = (signed char*)(ws + OFF_XQ8);
  float*          bpad   = (float*)(ws + OFF_BPAD);
  float*          sw8    = (float*)(ws + OFF_SW8);
  float*          w1     = (float*)(ws + OFF_W1);
  float*          invw   = (float*)(ws + OFF_IVW);
  int*            rowidx = (int*)(ws + OFF_ROWIDX);
  f32x4*          rmeta  = (f32x4*)(ws + OFF_RMETA);
  unsigned int*   counts = (unsigned int*)(ws + OFF_COUNTS);
  int*            amb    = (int*)(ws + OFF_AMB);
  Ctrl*           ctrl   = (Ctrl*)(ws + OFF_CTRL);
  int*            rk     = (int*)(ws + OFF_RK);
  float*          sst    = (float*)(ws + OFF_SST);

  // zero counts + amb + ctrl + rk (contiguous region)
  hipMemsetAsync(ws + OFF_COUNTS, 0, 32768 + 32768 + 16 + 32768, stream);

  k_prep2  <<<32, 256, 0, stream>>>(mask, rowidx, ctrl);
  k_wstat2 <<<800, 256, 0, stream>>>(W, b, sw8, w1, invw, bpad);
  k_twt8   <<<dim3(800, 8), 256, 0, stream>>>(W, invw, Wt8);
  k_xqt    <<<2048, 256, 0, stream>>>(x, rowidx, target, Wt8, bpad, sw8, w1,
                                      ctrl, Xq8, rmeta);
  k_count8 <<<12800, 256, 0, stream>>>(Xq8, Wt8, bpad, sw8, w1, rmeta,
                                       ctrl, counts);
  k_decide <<<32, 256, 0, stream>>>(counts, ctrl, amb);
  k_fixt   <<<128, 64, 0, stream>>>(x, W, b, rowidx, target, amb, ctrl, sst);
  k_fixscan<<<197, 256, 0, stream>>>(x, W, b, rowidx, target, amb, sst, ctrl, rk);
  k_fixdec <<<32, 256, 0, stream>>>(rk, ctrl);
  k_final  <<<1, 1, 0, stream>>>(ctrl, out);
}

// Round 18
// 431.645 us; speedup vs baseline: 1.0730x; 1.0730x over previous
//
#include <hip/hip_runtime.h>
#include <stdint.h>

// ---------------------------------------------------------------------------
// Problem constants
// ---------------------------------------------------------------------------
#define V_VOCAB 50257
#define V_PAD   51200          // 400 * 128
#define NROWS   8192           // 4 * 2048
#define DIM     512
#define KTOP    10
#define ACH     16             // amb rows per W-scan pass

typedef __attribute__((ext_vector_type(8))) short  short8;
typedef __attribute__((ext_vector_type(4))) float  f32x4;
typedef __attribute__((ext_vector_type(4))) int    i32x4;
typedef __attribute__((ext_vector_type(2))) unsigned int u32x2;

struct Ctrl { int mc; int namb; int hits; int pad_; };

// ws layout (bytes). Total ~31.6 MB.
#define OFF_WT8    0ULL
#define SZ_WT8     26214400ULL            // 51200*512 i8 (row = vocab col)
#define OFF_XQ8    (OFF_WT8 + SZ_WT8)
#define SZ_XQ8     4194304ULL             // 8192*512 i8
#define OFF_BPAD   (OFF_XQ8 + SZ_XQ8)
#define SZ_COL     (51200ULL*4)
#define OFF_SW8    (OFF_BPAD + SZ_COL)
#define OFF_W1     (OFF_SW8 + SZ_COL)
#define OFF_IVW    (OFF_W1 + SZ_COL)
#define OFF_ROWIDX (OFF_IVW + SZ_COL)
#define OFF_SXR    (OFF_ROWIDX + 32768ULL)
#define OFF_X1     (OFF_SXR + 32768ULL)
#define OFF_RMETA  (OFF_X1 + 32768ULL)    // f32x4 per row: {sx, that, etg', E}
#define OFF_COUNTS (OFF_RMETA + 131072ULL)
#define OFF_AMB    (OFF_COUNTS + 32768ULL)
#define OFF_CTRL   (OFF_AMB + 32768ULL)
#define OFF_RK     (OFF_CTRL + 16ULL)
#define OFF_SST    (OFF_RK + 32768ULL)

#define GLOAD16(gp, lp) __builtin_amdgcn_global_load_lds( \
    (const __attribute__((address_space(1))) unsigned int*)(gp), \
    (__attribute__((address_space(3))) unsigned int*)(lp), 16, 0, 0)

// ---------------------------------------------------------------------------
// 1. prep: bpad (-1e30 on pad cols) + masked-row compaction  [R16 version]
// ---------------------------------------------------------------------------
__global__ void k_prep(const int* __restrict__ mask, const float* __restrict__ b,
                       float* __restrict__ bpad, int* __restrict__ rowidx,
                       Ctrl* __restrict__ ctrl) {
  int i = blockIdx.x * 256 + threadIdx.x;
  if (i < V_PAD) bpad[i] = (i < V_VOCAB) ? b[i] : -1e30f;
  if (i < NROWS && mask[i] != 0) {
    int p = atomicAdd(&ctrl->mc, 1);
    rowidx[p] = i;
  }
}

// ---------------------------------------------------------------------------
// 2a. per-col stats [R16 version: 200 blocks, full-width 1KB-coalesced reads
//     — R17's 4-way k-split narrowed coalescing to 256B and regressed]
// ---------------------------------------------------------------------------
__global__ void k_wstat(const float* __restrict__ W, float* __restrict__ sw8,
                        float* __restrict__ w1, float* __restrict__ invw) {
  const int j = blockIdx.x * 256 + threadIdx.x;
  if (j >= V_PAD) return;
  if (j >= V_VOCAB) { sw8[j] = 1.f; w1[j] = 0.f; invw[j] = 0.f; return; }
  float am = 0.f, s1 = 0.f;
  for (int k = 0; k < DIM; ++k) {
    float v = fabsf(W[(size_t)k * V_VOCAB + j]);
    am = fmaxf(am, v);
    s1 += v;
  }
  sw8[j] = (am > 0.f) ? am / 126.f : 1.f;
  invw[j] = (am > 0.f) ? 126.f / am : 0.f;
  w1[j] = s1;
}

// ---------------------------------------------------------------------------
// 2b. transpose+quantize: W f32[512][V] -> Wt8 i8[V_PAD][512]
// ---------------------------------------------------------------------------
__global__ void k_twt8(const float* __restrict__ W, const float* __restrict__ invw,
                       signed char* __restrict__ Wt8) {
  __shared__ float lt[64][65];
  const int vbase = blockIdx.x * 64;
  const int kbase = blockIdx.y * 64;
  const int tid = threadIdx.x;
  const int krow = tid >> 6;
  const int col  = tid & 63;
  const int v    = vbase + col;
#pragma unroll
  for (int rr = 0; rr < 16; ++rr) {
    int kl = krow + rr * 4;
    float val = (v < V_VOCAB) ? W[(size_t)(kbase + kl) * V_VOCAB + v] : 0.0f;
    lt[kl][col] = val;
  }
  __syncthreads();
  const int vr = tid >> 3;        // 0..31
  const int kc = tid & 7;
#pragma unroll
  for (int p = 0; p < 2; ++p) {
    const int vl = p * 32 + vr;
    const float inv = invw[vbase + vl];
    unsigned int lo = 0, hi = 0;
#pragma unroll
    for (int j = 0; j < 4; ++j) {
      int q = (int)rintf(lt[kc * 8 + j][vl] * inv);
      lo |= ((unsigned int)(q & 255)) << (8 * j);
    }
#pragma unroll
    for (int j = 0; j < 4; ++j) {
      int q = (int)rintf(lt[kc * 8 + 4 + j][vl] * inv);
      hi |= ((unsigned int)(q & 255)) << (8 * j);
    }
    u32x2 t; t.x = lo; t.y = hi;
    *(u32x2*)(Wt8 + (size_t)(vbase + vl) * DIM + kbase + kc * 8) = t;
  }
}

// ---------------------------------------------------------------------------
// 3. quantize compacted x rows: Xq8 i8[8192][512] + sxr, x1 per row  [R16]
// ---------------------------------------------------------------------------
__global__ void k_xq(const float* __restrict__ x, const int* __restrict__ rowidx,
                     const Ctrl* __restrict__ ctrl, signed char* __restrict__ Xq8,
                     float* __restrict__ sxr, float* __restrict__ x1) {
  const int wid = threadIdx.x >> 6, lane = threadIdx.x & 63;
  const int i = blockIdx.x * 4 + wid;
  const int mc = ctrl->mc;
  if (i >= mc) {
    u32x2 z; z.x = 0; z.y = 0;
    *(u32x2*)(Xq8 + (size_t)i * DIM + lane * 8) = z;
    if (lane == 0) { sxr[i] = 1.f; x1[i] = 0.f; }
    return;
  }
  const float* src = x + (size_t)rowidx[i] * DIM + lane * 8;
  float v[8];
  float am = 0.f, s1 = 0.f;
#pragma unroll
  for (int j = 0; j < 8; ++j) {
    v[j] = src[j];
    float a = fabsf(v[j]);
    am = fmaxf(am, a);
    s1 += a;
  }
#pragma unroll
  for (int d = 1; d < 64; d <<= 1) {
    am = fmaxf(am, __shfl_xor(am, d, 64));
    s1 += __shfl_xor(s1, d, 64);
  }
  const float sx  = (am > 0.f) ? am / 126.f : 1.f;
  const float inv = (am > 0.f) ? 126.f / am : 0.f;
  unsigned int lo = 0, hi = 0;
#pragma unroll
  for (int j = 0; j < 4; ++j) {
    int q = (int)rintf(v[j] * inv);
    lo |= ((unsigned int)(q & 255)) << (8 * j);
  }
#pragma unroll
  for (int j = 0; j < 4; ++j) {
    int q = (int)rintf(v[4 + j] * inv);
    hi |= ((unsigned int)(q & 255)) << (8 * j);
  }
  u32x2 t; t.x = lo; t.y = hi;
  *(u32x2*)(Xq8 + (size_t)i * DIM + lane * 8) = t;
  if (lane == 0) { sxr[i] = sx; x1[i] = s1; }
}

// ---------------------------------------------------------------------------
// 4. exact-i8 target score + packed row meta  [R16 version]
//    rmeta[i] = {sx, that, etg + 1e-3 slop, E = 0.5005*x1 + 128.5*sx}.
// ---------------------------------------------------------------------------
__global__ void k_that8(const signed char* __restrict__ Xq8,
                        const signed char* __restrict__ Wt8,
                        const float* __restrict__ bpad, const float* __restrict__ sw8,
                        const float* __restrict__ w1,
                        const float* __restrict__ sxr, const float* __restrict__ x1,
                        const int* __restrict__ rowidx, const int* __restrict__ target,
                        const Ctrl* __restrict__ ctrl, f32x4* __restrict__ rmeta) {
  const int wid = threadIdx.x >> 6, lane = threadIdx.x & 63;
  const int i = blockIdx.x * 4 + wid;
  const int mc = ctrl->mc;
  if (i >= mc) {
    if (lane == 0) { f32x4 rm; rm.x = 1.f; rm.y = 1e30f; rm.z = 0.f; rm.w = 0.f; rmeta[i] = rm; }
    return;
  }
  const int tg = target[rowidx[i]];
  u32x2 xq = *(const u32x2*)(Xq8 + (size_t)i * DIM + lane * 8);
  u32x2 wq = *(const u32x2*)(Wt8 + (size_t)tg * DIM + lane * 8);
  int d = 0;
#pragma unroll
  for (int j = 0; j < 4; ++j)
    d += (int)((signed char)(xq.x >> (8 * j))) * (int)((signed char)(wq.x >> (8 * j)));
#pragma unroll
  for (int j = 0; j < 4; ++j)
    d += (int)((signed char)(xq.y >> (8 * j))) * (int)((signed char)(wq.y >> (8 * j)));
#pragma unroll
  for (int dd = 1; dd < 64; dd <<= 1) d += __shfl_xor(d, dd, 64);
  if (lane == 0) {
    const float sx = sxr[i], sw = sw8[tg], xl1 = x1[i];
    f32x4 rm;
    rm.x = sx;
    rm.y = fmaf((float)d, sx * sw, bpad[tg]);                       // that
    rm.z = 0.5005f * (sx * w1[tg] + sw * xl1) + 128.5f * (sx * sw)  // etg
           + 1e-3f;                                                 // + fp slop
    rm.w = fmaf(128.5f, sx, 0.5005f * xl1);                         // E
    rmeta[i] = rm;
  }
}

// ---------------------------------------------------------------------------
// 5. fused i8 GEMM-count  [R17 version — measured 253 us]:
//    128x128 tile, BK=128 i8, SINGLE 32KB LDS buffer, launch_bounds(256,3)
//    -> 3-resident spill-free; no setprio; skip trailing barrier when no
//    restage follows. Serial STAGE -> sync -> KTILE -> sync loop.
//    XOR slot swizzle via pre-swizzled source; 4 m-tiles pinned per XCD.
// ---------------------------------------------------------------------------
__launch_bounds__(256, 3)
__global__ void k_count8(const signed char* __restrict__ Xq8,
                         const signed char* __restrict__ Wt8,
                         const float* __restrict__ bpad, const float* __restrict__ sw8,
                         const float* __restrict__ w1, const f32x4* __restrict__ rmeta,
                         const Ctrl* __restrict__ ctrl, unsigned int* __restrict__ counts) {
  const int mc = ctrl->mc;
  // 12800 blocks = 8 XCDs x (4 m-tiles x 400 n-tiles), n-sweep per XCD
  const int lin = blockIdx.x;
  const int xcd = lin & 7;
  const int idx = lin >> 3;              // 0..1599
  const int mt  = xcd * 4 + (idx & 3);   // 0..31
  const int nt  = idx >> 2;              // 0..399
  const int nbase = nt * 128;

  __shared__ char lds[32768];            // single buffer: A 16KB + B 16KB

  const int tid  = threadIdx.x;
  const int lane = tid & 63;
  const int w    = tid >> 6;
  const int wr   = w >> 1;               // 0..1 : 64-row block
  const int wc   = w & 1;                // 0..1 : 64-col block

  const char* Bg = (const char*)Wt8 + (size_t)nbase * 512;
  const int r8   = tid >> 3;                                 // 0..31
  const int sws  = ((tid & 7) ^ (r8 & 7)) * 16;              // pre-swizzled src slot
  const int dst0 = tid * 16;

  const int fr = lane & 15;
  const int fq = lane >> 4;
  const int p0 = ((fq) ^ (fr & 7)) * 16;        // phys byte slot, k 0..63
  const int p1 = ((4 + fq) ^ (fr & 7)) * 16;    // k 64..127

#define STAGE(Ag, kt) do {                                                     \
    const size_t _kb = (size_t)(kt) * 128;                                     \
    _Pragma("unroll") for (int _c = 0; _c < 4; ++_c)                           \
      GLOAD16((Ag) + (size_t)(_c * 32 + r8) * 512 + _kb + sws,                 \
              lds + _c * 4096 + dst0);                                         \
    _Pragma("unroll") for (int _c = 0; _c < 4; ++_c)                           \
      GLOAD16(Bg + (size_t)(_c * 32 + r8) * 512 + _kb + sws,                   \
              lds + 16384 + _c * 4096 + dst0);                                 \
  } while (0)

#define KTILE() do {                                                           \
    _Pragma("unroll") for (int _ks = 0; _ks < 2; ++_ks) {                      \
      const int _p = _ks ? p1 : p0;                                            \
      i32x4 a4[4], b4[4];                                                      \
      _Pragma("unroll") for (int _i = 0; _i < 4; ++_i)                         \
        a4[_i] = *(const i32x4*)(lds + (wr * 64 + _i * 16 + fr) * 128 + _p);   \
      _Pragma("unroll") for (int _i = 0; _i < 4; ++_i)                         \
        b4[_i] = *(const i32x4*)(lds + 16384 +                                 \
                                 (wc * 64 + _i * 16 + fr) * 128 + _p);         \
      _Pragma("unroll") for (int _m = 0; _m < 4; ++_m)                         \
      _Pragma("unroll") for (int _n = 0; _n < 4; ++_n)                         \
        acc[_m][_n] = __builtin_amdgcn_mfma_i32_16x16x64_i8(                   \
            a4[_m], b4[_n], acc[_m][_n], 0, 0, 0);                             \
    }                                                                          \
  } while (0)

  i32x4 acc[4][4];

  // col meta (coalesced, loop-invariant)
  float bv[4], swc[4], w1c[4];
#pragma unroll
  for (int ni = 0; ni < 4; ++ni) {
    const int c = nbase + wc * 64 + ni * 16 + fr;
    bv[ni] = bpad[c]; swc[ni] = sw8[c]; w1c[ni] = w1[c];
  }

  for (int mb = mt * 128; mb < mc; mb += 4096) {
    const char* Ag = (const char*)Xq8 + (size_t)mb * 512;
#pragma unroll
    for (int a = 0; a < 4; ++a)
#pragma unroll
      for (int c = 0; c < 4; ++c) acc[a][c] = (i32x4)0;

#pragma unroll
    for (int kt = 0; kt < 4; ++kt) {
      STAGE(Ag, kt);
      __syncthreads();          // stage visible (compiler drains vmcnt)
      KTILE();
      if (kt < 3 || mb + 4096 < mc)
        __syncthreads();        // reads done before next stage overwrites
    }

    // epilogue: exact i32 -> f32 score, 2-fmaf margin, count, reduce, atomic
#pragma unroll
    for (int mi = 0; mi < 4; ++mi) {
#pragma unroll
      for (int r = 0; r < 4; ++r) {
        const int m = mb + wr * 64 + mi * 16 + fq * 4 + r;
        const f32x4 rm = rmeta[m];            // {sx, that, etg', E}
        const float arr = 0.5005f * rm.x;
        unsigned int p = 0;
#pragma unroll
        for (int ni = 0; ni < 4; ++ni) {
          const float s  = fmaf((float)acc[mi][ni][r], rm.x * swc[ni], bv[ni]);
          const float mm = fmaf(arr, w1c[ni], fmaf(rm.w, swc[ni], rm.z));
          p += (s > rm.y - mm) ? 1u : 0u;
          p += (s > rm.y + mm) ? (1u << 16) : 0u;
        }
        int pi = (int)p;
#pragma unroll
        for (int d = 1; d < 16; d <<= 1) pi += __shfl_xor(pi, d, 64);
        if ((lane & 15) == 0) atomicAdd(&counts[m], (unsigned int)pi);
      }
    }
  }
#undef STAGE
#undef KTILE
}

// ---------------------------------------------------------------------------
// 6. decide: certain hit / certain miss / ambiguous
// ---------------------------------------------------------------------------
__global__ void k_decide(const unsigned int* __restrict__ counts,
                         Ctrl* __restrict__ ctrl, int* __restrict__ amb) {
  const int i = blockIdx.x * 256 + threadIdx.x;
  if (i >= ctrl->mc) return;
  const unsigned int c = counts[i];
  const unsigned int lo = c & 0xFFFFu, hi = c >> 16;
  if (lo <= KTOP - 1) { atomicAdd(&ctrl->hits, 1); }
  else if (hi >= KTOP) { /* certain miss */ }
  else { int p = atomicAdd(&ctrl->namb, 1); amb[p] = i; }
}

// ---------------------------------------------------------------------------
// 7a. fixup targets (exact f32, sequential fmaf chain — must match k_fixscan)
// ---------------------------------------------------------------------------
__global__ void k_fixt(const float* __restrict__ x, const float* __restrict__ W,
                       const float* __restrict__ b, const int* __restrict__ rowidx,
                       const int* __restrict__ target, const int* __restrict__ amb,
                       const Ctrl* __restrict__ ctrl, float* __restrict__ sst) {
  const int a = blockIdx.x * 64 + threadIdx.x;
  if (a >= ctrl->namb) return;
  const int n = rowidx[amb[a]];
  const int tg = target[n];
  float st = 0.f;
  for (int k = 0; k < DIM; ++k)
    st = fmaf(x[(size_t)n * DIM + k], W[(size_t)k * V_VOCAB + tg], st);
  sst[a] = st + b[tg];
}

// ---------------------------------------------------------------------------
// 7b. fixup scan: one coalesced streaming pass over W for <=ACH rows at a time
// ---------------------------------------------------------------------------
__global__ void k_fixscan(const float* __restrict__ x, const float* __restrict__ W,
                          const float* __restrict__ b, const int* __restrict__ rowidx,
                          const int* __restrict__ target, const int* __restrict__ amb,
                          const float* __restrict__ sst, const Ctrl* __restrict__ ctrl,
                          int* __restrict__ rk) {
  __shared__ float sx[ACH][DIM];
  const int j = blockIdx.x * 256 + threadIdx.x;
  const int namb = ctrl->namb;
  const float bj = (j < V_VOCAB) ? b[j] : 0.f;
  for (int base = 0; base < namb; base += ACH) {
    __syncthreads();
    for (int t = threadIdx.x; t < ACH * DIM / 4; t += 256) {
      const int a  = t / (DIM / 4);
      const int kk = (t % (DIM / 4)) * 4;
      f32x4 v = (f32x4)0.f;
      if (base + a < namb) {
        const int n = rowidx[amb[base + a]];
        v = *(const f32x4*)(x + (size_t)n * DIM + kk);
      }
      *(f32x4*)(&sx[a][kk]) = v;
    }
    __syncthreads();
    if (j >= V_VOCAB) continue;
    float s[ACH];
#pragma unroll
    for (int a = 0; a < ACH; ++a) s[a] = 0.f;
    for (int k = 0; k < DIM; ++k) {
      const float wv = W[(size_t)k * V_VOCAB + j];
#pragma unroll
      for (int a = 0; a < ACH; ++a) s[a] = fmaf(sx[a][k], wv, s[a]);
    }
#pragma unroll
    for (int a = 0; a < ACH; ++a) {
      if (base + a < namb) {
        const int tg = target[rowidx[amb[base + a]]];
        const float sc = s[a] + bj;
        const float st = sst[base + a];
        if (sc > st || (sc == st && j < tg)) atomicAdd(&rk[base + a], 1);
      }
    }
  }
}

// ---------------------------------------------------------------------------
// 7c. fixup decide
// ---------------------------------------------------------------------------
__global__ void k_fixdec(const int* __restrict__ rk, Ctrl* __restrict__ ctrl) {
  const int a = blockIdx.x * 256 + threadIdx.x;
  if (a < ctrl->namb && rk[a] <= KTOP - 1) atomicAdd(&ctrl->hits, 1);
}

// ---------------------------------------------------------------------------
// 8. finalize
// ---------------------------------------------------------------------------
__global__ void k_final(const Ctrl* __restrict__ ctrl, float* __restrict__ out) {
  out[0] = (float)ctrl->hits / (float)ctrl->mc;
}

// ---------------------------------------------------------------------------
extern "C" void kernel_launch(void* const* d_in, const int* in_sizes, int n_in,
                              void* d_out, int out_size, void* d_ws, size_t ws_size,
                              hipStream_t stream) {
  const float* x      = (const float*)d_in[0];   // [8192, 512]
  const int*   target = (const int*)d_in[1];     // [8192]
  const int*   mask   = (const int*)d_in[2];     // [8192]
  const float* W      = (const float*)d_in[3];   // [512, 50257]
  const float* b      = (const float*)d_in[4];   // [50257]
  float* out = (float*)d_out;

  char* ws = (char*)d_ws;
  signed char*    Wt8    = (signed char*)(ws + OFF_WT8);
  signed char*    Xq8    = (signed char*)(ws + OFF_XQ8);
  float*          bpad   = (float*)(ws + OFF_BPAD);
  float*          sw8    = (float*)(ws + OFF_SW8);
  float*          w1     = (float*)(ws + OFF_W1);
  float*          invw   = (float*)(ws + OFF_IVW);
  int*            rowidx = (int*)(ws + OFF_ROWIDX);
  float*          sxr    = (float*)(ws + OFF_SXR);
  float*          x1     = (float*)(ws + OFF_X1);
  f32x4*          rmeta  = (f32x4*)(ws + OFF_RMETA);
  unsigned int*   counts = (unsigned int*)(ws + OFF_COUNTS);
  int*            amb    = (int*)(ws + OFF_AMB);
  Ctrl*           ctrl   = (Ctrl*)(ws + OFF_CTRL);
  int*            rk     = (int*)(ws + OFF_RK);
  float*          sst    = (float*)(ws + OFF_SST);

  // zero counts + amb + ctrl + rk (contiguous region)
  hipMemsetAsync(ws + OFF_COUNTS, 0, 32768 + 32768 + 16 + 32768, stream);

  k_prep   <<<200, 256, 0, stream>>>(mask, b, bpad, rowidx, ctrl);
  k_wstat  <<<200, 256, 0, stream>>>(W, sw8, w1, invw);
  k_twt8   <<<dim3(800, 8), 256, 0, stream>>>(W, invw, Wt8);
  k_xq     <<<2048, 256, 0, stream>>>(x, rowidx, ctrl, Xq8, sxr, x1);
  k_that8  <<<2048, 256, 0, stream>>>(Xq8, Wt8, bpad, sw8, w1, sxr, x1,
                                      rowidx, target, ctrl, rmeta);
  k_count8 <<<12800, 256, 0, stream>>>(Xq8, Wt8, bpad, sw8, w1, rmeta,
                                       ctrl, counts);
  k_decide <<<32, 256, 0, stream>>>(counts, ctrl, amb);
  k_fixt   <<<128, 64, 0, stream>>>(x, W, b, rowidx, target, amb, ctrl, sst);
  k_fixscan<<<197, 256, 0, stream>>>(x, W, b, rowidx, target, amb, sst, ctrl, rk);
  k_fixdec <<<32, 256, 0, stream>>>(rk, ctrl);
  k_final  <<<1, 1, 0, stream>>>(ctrl, out);
}